// Round 6
// baseline (315.700 us; speedup 1.0000x reference)
//
#include <hip/hip_runtime.h>

// VQ-VAE quantization: z [16384 x 512] f32, codebook [8192 x 512] f32.
// out = concat(z_st [16384*512] f32, vq_loss [1] f32).
//
// R4: MX-fp8 (e4m3, K=128 scaled MFMA) scores GEMM; packed (dist|idx) u32
// argmin. R6: spill fix + candV [ktile][row]. R8: XCD remap + dbuf + loss
// partials. R9 (this): deep-block restructure to break the ~900TF-equiv
// 2-barrier ceiling:
//  - 1 block = 1 ktile: B-tile (64KB, all K) LDS-resident, staged once;
//    8 mtiles streamed via 2-slot A dbuf (32KB). Grid 8192 -> 1024 blocks
//    (4 rounds/CU): 4 cold prologues instead of 16, fetch/CU halved.
//  - counted vmcnt (T4): raw s_barrier + "s_waitcnt vmcnt(2)" waits only
//    for the stage issued one full compute-phase ago; in-flight prefetch
//    is never drained (no __syncthreads in K-loop). Epilogue's
//    __syncthreads re-zeroes the vmcnt bookkeeping per mtile.
//  - 512 thr / 8 waves (2/SIMD), per-wave tile 64x32 -> acc 32 VGPR.

#define M_ROWS 16384
#define K_CODES 8192
#define DIM 512
#define BM 128
#define BN 128
#define BK 128                 // fp8 bytes per K-step (one 16x16x128 MFMA)
#define KSTEPS 4               // DIM / BK
#define G_MT 8                 // mtiles per block
#define NT (K_CODES / BN)      // 64 candidate tiles per row
#define OUT0_SIZE (M_ROWS * DIM)
#define GB_BLOCKS 1024

typedef int   i32x8 __attribute__((ext_vector_type(8)));
typedef float f32x4 __attribute__((ext_vector_type(4)));

template <bool HI>
__device__ __forceinline__ int pk8(float a, float b, int old) {
    return __builtin_amdgcn_cvt_pk_fp8_f32(a, b, old, HI);
}

__device__ __forceinline__ void gload_lds(const unsigned char* g, unsigned char* l) {
    __builtin_amdgcn_global_load_lds((const __attribute__((address_space(1))) void*)g,
                                     (__attribute__((address_space(3))) void*)l, 16, 0, 0);
}

// ---- kernel 1: fused converts ------------------------------------------
__global__ __launch_bounds__(256) void convert_all(
    const float* __restrict__ z, const float* __restrict__ cb,
    unsigned char* __restrict__ z8, unsigned char* __restrict__ cb8,
    float* __restrict__ enorm)
{
    const int tid = threadIdx.x;
    if (blockIdx.x < K_CODES / 4) {
        const int w = tid >> 6, lane = tid & 63;
        const int row = blockIdx.x * 4 + w;
        const float* src = cb + (size_t)row * DIM + lane * 8;
        float4 a = *(const float4*)(src);
        float4 b = *(const float4*)(src + 4);
        float ns = a.x * a.x + a.y * a.y + a.z * a.z + a.w * a.w
                 + b.x * b.x + b.y * b.y + b.z * b.z + b.w * b.w;
        const float S = 8192.0f;                 // exact power of 2
        int lo = 0, hi = 0;
        lo = pk8<false>(a.x * S, a.y * S, lo); lo = pk8<true>(a.z * S, a.w * S, lo);
        hi = pk8<false>(b.x * S, b.y * S, hi); hi = pk8<true>(b.z * S, b.w * S, hi);
        *(int2*)(cb8 + (size_t)row * DIM + lane * 8) = make_int2(lo, hi);
        for (int m = 32; m; m >>= 1) ns += __shfl_down(ns, m, 64);
        if (lane == 0) enorm[row] = S * ns;      // 8192 * ||e||^2 (f32-exact norm)
    } else {
        size_t i = ((size_t)(blockIdx.x - K_CODES / 4) * 256 + tid) * 8;
        float4 a = *(const float4*)(z + i);
        float4 b = *(const float4*)(z + i + 4);
        int lo = 0, hi = 0;
        lo = pk8<false>(a.x, a.y, lo); lo = pk8<true>(a.z, a.w, lo);
        hi = pk8<false>(b.x, b.y, hi); hi = pk8<true>(b.z, b.w, hi);
        *(int2*)(z8 + i) = make_int2(lo, hi);
    }
}

// ---- kernel 2: deep-block MX-fp8 GEMM + packed-argmin ------------------
__global__ __launch_bounds__(512, 1) void gemm_argmin(
    const unsigned char* __restrict__ z8, const unsigned char* __restrict__ cb8,
    const float* __restrict__ enorm, unsigned int* __restrict__ candV)
{
    __shared__ alignas(32) unsigned char Bs[KSTEPS][BN * BK];  // 64 KB resident
    __shared__ alignas(32) unsigned char As[2][BM * BK];       // 32 KB dbuf
    __shared__ unsigned int cU[BM][4];                         // 2 KB

    const int tid = threadIdx.x;
    const int lane = tid & 63;
    const int w = tid >> 6;               // 0..7
    // XCD map: b&7 = XCD; 16 co-resident same-ktile blocks share B via L2.
    const int b = blockIdx.x;
    const int xcd = b & 7;
    const int idx = b >> 3;               // 0..127 within XCD
    const int ktile = xcd * 8 + (idx >> 4);
    const int mgroup = idx & 15;          // owns mtiles [mgroup*8, mgroup*8+8)
    const int nbase = ktile * BN;

    const int rA = lane >> 3;             // row within 8-row chunk
    const int jG = ((lane & 7) ^ rA) * 16;// pre-swizzled global 16B chunk
    const int quad = lane >> 4;
    const int l15 = lane & 15;
    const int sw = l15 & 7;
    const int wr = (w >> 2) * 64;         // wave row half: 0 / 64
    const int wc = (w & 3) * 32;          // wave col quarter: 0/32/64/96
    // Chunks c0=(2q)^sw, c1=c0^1 = one aligned 32B block (R3-proven: the
    // per-lane half-swap is identical for A and B -> dot product exact).
    const int t32 = ((quad << 1) ^ (sw & 6)) * 16;

    // per-ktile norms -> regs (oldest vmcnt ops; forced complete at s=0 wait)
    float es0 = enorm[nbase + wc + l15];
    float es1 = enorm[nbase + wc + 16 + l15];

    // stage B: all 4 K-subtiles, once (8 loads/thread)
#pragma unroll
    for (int ks = 0; ks < KSTEPS; ++ks)
#pragma unroll
        for (int i = 0; i < 2; ++i) {
            int c = w * 2 + i;            // chunk 0..15 (8 rows each)
            int row = c * 8 + rA;
            gload_lds(cb8 + (size_t)(nbase + row) * DIM + ks * BK + jG,
                      Bs[ks] + c * 1024 + lane * 16);
        }

#define STAGE_A(slot, m_, k_) do {                                            \
    _Pragma("unroll")                                                         \
    for (int i_ = 0; i_ < 2; ++i_) {                                          \
        int c_ = w * 2 + i_;                                                  \
        int row_ = c_ * 8 + rA;                                               \
        gload_lds(z8 + (size_t)((mgroup * G_MT + (m_)) * BM + row_) * DIM     \
                     + (k_) * BK + jG,                                        \
                  As[slot] + c_ * 1024 + lane * 16);                          \
    } } while (0)

    STAGE_A(0, 0, 0);                     // prefetch (m=0,k=0) into slot 0

    for (int m = 0; m < G_MT; ++m) {
        f32x4 acc[8];
#pragma unroll
        for (int i = 0; i < 8; ++i) acc[i] = (f32x4){0.f, 0.f, 0.f, 0.f};

#pragma unroll
        for (int k = 0; k < KSTEPS; ++k) {
            // close previous step's reads of the slot about to be written
            __builtin_amdgcn_s_barrier();
            __builtin_amdgcn_sched_barrier(0);   // pin stage below barrier
            if (k < KSTEPS - 1) {
                STAGE_A((k + 1) & 1, m, k + 1);
                asm volatile("s_waitcnt vmcnt(2)" ::: "memory");  // pre(k) done
            } else if (m < G_MT - 1) {
                STAGE_A(0, m + 1, 0);
                asm volatile("s_waitcnt vmcnt(2)" ::: "memory");
            } else {
                asm volatile("s_waitcnt vmcnt(0)" ::: "memory");  // final step
            }
            // fragments (slot parity = k&1 since 4m is even)
            i32x8 bf0 = *(const i32x8*)(Bs[k] + (wc + l15) * BK + t32);
            i32x8 bf1 = *(const i32x8*)(Bs[k] + (wc + 16 + l15) * BK + t32);
#pragma unroll
            for (int rf = 0; rf < 4; ++rf) {
                i32x8 a = *(const i32x8*)(As[k & 1] + (wr + rf * 16 + l15) * BK + t32);
                acc[rf * 2 + 0] = __builtin_amdgcn_mfma_scale_f32_16x16x128_f8f6f4(
                    a, bf0, acc[rf * 2 + 0], 0, 0, 0, 0x7F7F7F7F, 0, 0x7F7F7F7F);
                acc[rf * 2 + 1] = __builtin_amdgcn_mfma_scale_f32_16x16x128_f8f6f4(
                    a, bf1, acc[rf * 2 + 1], 0, 0, 0, 0x7F7F7F7F, 0, 0x7F7F7F7F);
            }
        }

        // epilogue for mtile m: per-row argmin over this ktile's 128 cols.
        // C/D layout: col = lane&15, row = quad*4 + reg.
        const int mb = (mgroup * G_MT + m) * BM;
#pragma unroll
        for (int rf = 0; rf < 4; ++rf) {
#pragma unroll
            for (int r = 0; r < 4; ++r) {
                float d0 = fmaf(-2.0f, acc[rf * 2 + 0][r], es0);
                float d1 = fmaf(-2.0f, acc[rf * 2 + 1][r], es1);
                // strict <: keeps lower col on tie (col0 < col1 always)
                float bv = d1 < d0 ? d1 : d0;
                int col = d1 < d0 ? wc + 16 + l15 : wc + l15;
                unsigned u = __builtin_bit_cast(unsigned, bv);
                u ^= ((unsigned)(((int)u) >> 31)) | 0x80000000u;
                unsigned key = (u & 0xFFFFE000u) | (unsigned)(nbase + col);
#pragma unroll
                for (int sh = 1; sh < 16; sh <<= 1) {
                    unsigned o = __shfl_xor(key, sh, 64);
                    key = o < key ? o : key;
                }
                if (l15 == 0) cU[wr + rf * 16 + quad * 4 + r][w & 3] = key;
            }
        }
        __syncthreads();   // cU visible; also drains vmcnt -> clean counting
        if (tid < BM) {
            unsigned k0 = cU[tid][0], k1 = cU[tid][1];
            unsigned k2 = cU[tid][2], k3 = cU[tid][3];
            unsigned ka = k0 < k1 ? k0 : k1;
            unsigned kb = k2 < k3 ? k2 : k3;
            candV[(size_t)ktile * M_ROWS + mb + tid] = ka < kb ? ka : kb;
        }
        // next mtile's cU writes are separated by >=4 barriers -> safe
    }
#undef STAGE_A
}

// ---- kernel 3: fused candidate-reduce + gather + ST output -------------
__global__ __launch_bounds__(256) void gather_out(
    const float* __restrict__ z, const float* __restrict__ cb,
    const unsigned int* __restrict__ candV, float* __restrict__ out,
    float* __restrict__ partials)
{
    __shared__ float red[4];
    const int tid = threadIdx.x;
    const int w = tid >> 6, lane = tid & 63;
    float lsum = 0.f;
#pragma unroll
    for (int it = 0; it < M_ROWS / (GB_BLOCKS * 4); ++it) {
        int row = (it * GB_BLOCKS + blockIdx.x) * 4 + w;
        unsigned key = candV[(size_t)lane * M_ROWS + row];
#pragma unroll
        for (int m = 1; m < 64; m <<= 1) {
            unsigned o = __shfl_xor(key, m, 64);
            key = o < key ? o : key;
        }
        int k = (int)(key & 8191u);
#pragma unroll
        for (int j = 0; j < 2; ++j) {
            int slot = lane + j * 64;
            float4 zv = ((const float4*)(z + (size_t)row * DIM))[slot];
            float4 cv = ((const float4*)(cb + (size_t)k * DIM))[slot];
            float dx = cv.x - zv.x, dy = cv.y - zv.y;
            float dz2 = cv.z - zv.z, dw = cv.w - zv.w;
            float4 o = {zv.x + dx, zv.y + dy, zv.z + dz2, zv.w + dw};  // z + sg(zq-z)
            ((float4*)(out + (size_t)row * DIM))[slot] = o;
            lsum += dx * dx + dy * dy + dz2 * dz2 + dw * dw;
        }
    }
    for (int m = 32; m; m >>= 1) lsum += __shfl_down(lsum, m, 64);
    if (lane == 0) red[w] = lsum;
    __syncthreads();
    if (tid == 0) partials[blockIdx.x] = (red[0] + red[1]) + (red[2] + red[3]);
}

// ---- kernel 4: final loss reduction (1024 partials -> scalar) ----------
__global__ __launch_bounds__(256) void reduce_loss(
    const float* __restrict__ partials, float* __restrict__ lossOut)
{
    __shared__ float red[4];
    const int tid = threadIdx.x;
    float s = 0.f;
#pragma unroll
    for (int i = 0; i < GB_BLOCKS / 256; ++i) s += partials[i * 256 + tid];
    for (int m = 32; m; m >>= 1) s += __shfl_down(s, m, 64);
    if ((tid & 63) == 0) red[tid >> 6] = s;
    __syncthreads();
    if (tid == 0)
        lossOut[0] = ((red[0] + red[1]) + (red[2] + red[3])) * (1.1f / (float)OUT0_SIZE);
}

extern "C" void kernel_launch(void* const* d_in, const int* in_sizes, int n_in,
                              void* d_out, int out_size, void* d_ws, size_t ws_size,
                              hipStream_t stream) {
    const float* z = (const float*)d_in[0];     // 16*1024*512
    const float* cb = (const float*)d_in[1];    // 8192*512
    float* out = (float*)d_out;                 // 8388608 + 1
    char* ws = (char*)d_ws;

    // ws layout (bytes)
    unsigned char* z8   = (unsigned char*)(ws);               //  8,388,608
    unsigned char* cb8  = (unsigned char*)(ws + 8388608);     //  4,194,304
    float* enorm        = (float*)(ws + 12582912);            //     32,768
    unsigned int* candV = (unsigned int*)(ws + 12615680);     //  4,194,304
    float* partials     = (float*)(ws + 16809984);            //      4,096

    convert_all<<<K_CODES / 4 + M_ROWS * DIM / 2048, 256, 0, stream>>>(
        z, cb, z8, cb8, enorm);
    gemm_argmin<<<NT * (M_ROWS / BM) / G_MT, 512, 0, stream>>>(z8, cb8, enorm, candV);
    gather_out<<<GB_BLOCKS, 256, 0, stream>>>(z, cb, candV, out, partials);
    reduce_loss<<<1, 256, 0, stream>>>(partials, out + OUT0_SIZE);
}